// Round 22
// baseline (356.573 us; speedup 1.0000x reference)
//
#include <hip/hip_runtime.h>

// HierarchicalCSNet — f16 MFMA implicit-GEMM, 13 dispatches.
// Consolidation: R20 kernel set (separate h1; single-mode fus with LDS rtile
// hcomp) + R21's 4-block/CU t5. R19/R21 double-confirmed: folding h1 into
// fus#1 is net-negative (template instantiation runs 45us slower) — dropped.
constexpr int H = 256, W = 256, NPIX = H * W;
constexpr int PW = 258;
constexpr size_t PLANE = (size_t)PW * PW * 64;

typedef _Float16 half8 __attribute__((ext_vector_type(8)));
typedef _Float16 half4 __attribute__((ext_vector_type(4)));
typedef float    f32x4 __attribute__((ext_vector_type(4)));
typedef float    f32x16 __attribute__((ext_vector_type(16)));

__device__ __forceinline__ void gl16(const _Float16* g, _Float16* l)
{
    __builtin_amdgcn_global_load_lds(
        (const __attribute__((address_space(1))) unsigned int*)g,
        (__attribute__((address_space(3))) unsigned int*)l, 16, 0, 0);
}

// ---------- prep: border zero + weight prep + sampup (grid 512)
__global__ __launch_bounds__(256)
void prep_k(const float* __restrict__ x, const float* __restrict__ sw,
            const float* __restrict__ uw, const float* __restrict__ ub,
            const float* __restrict__ t2w, const float* __restrict__ t3w,
            const float* __restrict__ t4w, const float* __restrict__ fusw,
            _Float16* __restrict__ planes, _Float16* __restrict__ w16,
            float* __restrict__ r_all)
{
    const int b = blockIdx.x, t = threadIdx.x;
    for (int idx = b * 256 + t; idx < 24 * 1028 * 8; idx += 512 * 256) {
        int c = idx & 7, rem = idx >> 3;
        int p = rem / 1028, bb = rem % 1028;
        int gy, gx;
        if (bb < 258)      { gy = 0;            gx = bb; }
        else if (bb < 516) { gy = 257;          gx = bb - 258; }
        else if (bb < 772) { gy = bb - 516 + 1; gx = 0; }
        else               { gy = bb - 772 + 1; gx = 257; }
        f32x4 z = {0.f, 0.f, 0.f, 0.f};
        *(f32x4*)(planes + (size_t)p * PLANE + ((size_t)(gy * PW + gx) * 64) + c * 8) = z;
    }
    for (int idx = b * 256 + t; idx < 38 * 36864; idx += 512 * 256) {
        int blk = idx / 36864, r2 = idx % 36864;
        int e = r2 & 7, co = (r2 >> 3) & 63, hh = (r2 >> 9) & 1, kk = (r2 >> 10) & 3,
            tap = r2 >> 12;
        const float* src; int cin, cib;
        if (blk < 24) {
            int which = blk >> 3, m = blk & 7;
            src = (which == 0 ? t2w : which == 1 ? t3w : t4w) + (size_t)m * 64 * 64 * 9;
            cin = 64; cib = 0;
        } else {
            int f = (blk - 24) >> 1; cib = ((blk - 24) & 1) * 64;
            src = fusw + (size_t)f * 64 * 128 * 9; cin = 128;
        }
        int ci = cib + (kk * 2 + hh) * 8 + e;
        w16[idx] = (_Float16)src[((size_t)co * cin + ci) * 9 + tap];
    }
    {
        int m = b >> 6, ij = b & 63;
        int i = ij >> 3, j = ij & 7;
        __shared__ float s_lds[16];
        if (t < 208) {
            int c = t >> 4, sub = t & 15;
            float acc = 0.f;
            for (int k = sub * 64; k < sub * 64 + 64; ++k) {
                int p = k >> 5, q = k & 31;
                acc += x[(i * 32 + p) * W + (j * 32 + q)] * sw[(m * 13 + c) * 1024 + k];
            }
            #pragma unroll
            for (int off = 8; off; off >>= 1) acc += __shfl_down(acc, off, 16);
            if (sub == 0) s_lds[c] = acc;
        }
        __syncthreads();
        const float* uwm = uw + m * 1024 * 13;
        float* rm = r_all + m * NPIX;
        #pragma unroll
        for (int pi = 0; pi < 4; ++pi) {
            int px = pi * 256 + t;
            int p = px >> 5, q = px & 31;
            int oc = p * 32 + q;
            float acc = ub[m * 1024 + oc];
            #pragma unroll
            for (int c = 0; c < 13; ++c) acc = fmaf(uwm[oc * 13 + c], s_lds[c], acc);
            rm[((i * 32 + p) << 8) + j * 32 + q] = acc;
        }
    }
}

// ---------------- h1 (m=0 only): conv 1->64, writes padded plane f_all[0]
__global__ __launch_bounds__(256)
void h1_k(const float* __restrict__ r_all, const float* __restrict__ w,
          const float* __restrict__ b, const float* __restrict__ a,
          _Float16* __restrict__ f0)
{
    const float* r = r_all;
    const int t = threadIdx.x;
    const int px = t & 63, cog = t >> 6;
    const int y = blockIdx.x >> 2;
    const int x = ((blockIdx.x & 3) << 6) + px;
    float v[9];
    #pragma unroll
    for (int dy = 0; dy < 3; ++dy) {
        int gy = y + dy - 1;
        #pragma unroll
        for (int dx = 0; dx < 3; ++dx) {
            int gx = x + dx - 1;
            v[dy*3+dx] = ((unsigned)gy < 256u && (unsigned)gx < 256u)
                       ? r[(gy << 8) + gx] : 0.f;
        }
    }
    const float slope = a[0];
    _Float16* op = f0 + ((size_t)((y + 1) * PW + (x + 1))) * 64 + cog * 16;
    #pragma unroll
    for (int cg2 = 0; cg2 < 2; ++cg2) {
        half8 o;
        #pragma unroll
        for (int j = 0; j < 8; ++j) {
            int co = cog * 16 + cg2 * 8 + j;
            float acc = b[co];
            #pragma unroll
            for (int k = 0; k < 9; ++k) acc = fmaf(v[k], w[co*9+k], acc);
            acc = acc >= 0.f ? acc : slope * acc;
            o[j] = (_Float16)acc;
        }
        *(half8*)(op + cg2 * 8) = o;
    }
}

// ------------------------- batched conv3x3 (t2/t3/t4): R13-proven version
__global__ __launch_bounds__(256, 2)
void conv_mfma_k(const _Float16* __restrict__ in0, const _Float16* __restrict__ w0,
                 const float* __restrict__ bias, const float* __restrict__ alpha,
                 _Float16* __restrict__ out)
{
    const int t    = threadIdx.x;
    const int lane = t & 63;
    const int wv   = t >> 6;
    const int b    = blockIdx.x;
    const int m    = b >> 6;
    const int rem  = b & 63;
    const int xh   = rem & 1;
    const int y0   = (rem >> 1) << 3;

    const _Float16* inp0 = in0 + (size_t)m * PLANE;
    _Float16*       outp = out + (size_t)m * PLANE;
    const _Float16* wp0  = w0 + (size_t)m * 36864;
    const float*    bp   = bias + m * 64;
    const float     slope = alpha[m];
    const int x0 = xh << 7;

    const int h = lane >> 5, cl = lane & 31;
    const int px0 = (wv & 1) * 64, cobase = (wv >> 1) * 32;

    extern __shared__ __align__(16) char smem[];
    _Float16* li = (_Float16*)smem;            // ring [4][130][8][8] = 66560 B

    half8 Areg[36];
    #pragma unroll
    for (int tap = 0; tap < 9; ++tap)
        #pragma unroll
        for (int kk = 0; kk < 4; ++kk)
            Areg[tap*4+kk] = *(const half8*)(wp0 +
                (size_t)(((tap*4+kk)*2 + h)*64 + cobase + cl) * 8);

    auto stage_row = [&](int pr) {
        const int slot = pr & 3;
        #pragma unroll
        for (int i = 0; i < 5; ++i) {
            int f = i * 256 + t;
            if (i < 4 || f < 1040) {
                int hx = f >> 3, c = f & 7;
                gl16(inp0 + ((size_t)(pr * PW + x0 + hx) * 64 + (c ^ (hx & 7)) * 8),
                     li + (size_t)(slot * 1040 + f) * 8);
            }
        }
    };

    f32x16 acc0, acc1;

    stage_row(y0); stage_row(y0 + 1); stage_row(y0 + 2);
    __syncthreads();
    #pragma unroll 1
    for (int s = 0; s < 8; ++s) {
        if (s < 7) stage_row(y0 + s + 3);
        #pragma unroll
        for (int q = 0; q < 4; ++q)
            #pragma unroll
            for (int j = 0; j < 4; ++j) {
                float bb = bp[cobase + q * 8 + 4 * h + j];
                acc0[q*4+j] = bb; acc1[q*4+j] = bb;
            }
        __builtin_amdgcn_s_setprio(1);
        #pragma unroll
        for (int tap = 0; tap < 9; ++tap) {
            const int dy = tap / 3, dx = tap % 3;
            const int slot = (y0 + s + dy) & 3;
            const int hx0 = px0 + cl + dx;
            const int hx1 = hx0 + 32;
            const int sw8 = hx0 & 7;
            #pragma unroll
            for (int kk = 0; kk < 4; ++kk) {
                const int c = kk * 2 + h;
                half8 b0 = *(const half8*)(li + ((size_t)((slot*130 + hx0)*8 + (c ^ sw8))) * 8);
                half8 b1 = *(const half8*)(li + ((size_t)((slot*130 + hx1)*8 + (c ^ sw8))) * 8);
                acc0 = __builtin_amdgcn_mfma_f32_32x32x16_f16(Areg[tap*4+kk], b0, acc0, 0, 0, 0);
                acc1 = __builtin_amdgcn_mfma_f32_32x32x16_f16(Areg[tap*4+kk], b1, acc1, 0, 0, 0);
            }
        }
        __builtin_amdgcn_s_setprio(0);
        const int y = y0 + s;
        #pragma unroll
        for (int pt = 0; pt < 2; ++pt) {
            const size_t gp = (size_t)((y + 1) * PW + (x0 + px0 + pt * 32 + cl + 1)) * 64;
            const f32x16& A0 = pt ? acc1 : acc0;
            #pragma unroll
            for (int q = 0; q < 4; ++q) {
                half4 v0;
                #pragma unroll
                for (int j = 0; j < 4; ++j) {
                    float xv = A0[q*4+j];
                    xv = xv >= 0.f ? xv : slope * xv;
                    v0[j] = (_Float16)xv;
                }
                *(half4*)(outp + gp + cobase + q * 8 + 4 * h) = v0;
            }
        }
        if (s < 7) {
            asm volatile("s_waitcnt vmcnt(8)" ::: "memory");
            __builtin_amdgcn_s_barrier();
            __builtin_amdgcn_sched_barrier(0);
        }
    }
}

// ---------------------- fusion (m>=1): hcomp reads r-window from LDS rtile
__global__ __launch_bounds__(256, 2)
void fus_k(const _Float16* __restrict__ fprev, const float* __restrict__ rm,
           const float* __restrict__ h1w, const float* __restrict__ h1b,
           const float* __restrict__ h1a,
           const _Float16* __restrict__ wf, const _Float16* __restrict__ wh,
           const float* __restrict__ bias, const float* __restrict__ alpha,
           _Float16* __restrict__ outp)
{
    const int t = threadIdx.x, lane = t & 63, wv = t >> 6;
    const int b = blockIdx.x;
    const int xcd = b & 7, u = b >> 3, xq = u & 3, band = u >> 2;
    const int y0 = xcd * 32 + band * 2, x0 = xq * 64;
    const int h = lane >> 5, cl = lane & 31;
    const int px0 = (wv & 1) * 32, cobase = (wv >> 1) * 32;

    __shared__ __align__(16) _Float16 ringF[4 * 528 * 8];   // 33792 B
    __shared__ __align__(16) _Float16 ringH[4 * 528 * 8];   // 33792 B
    __shared__ float rtile[6 * 68];                         //  1632 f32

    // 1. issue f_prev staging early (stays in flight through hcomp)
    #pragma unroll
    for (int i = 0; i < 9; ++i) {
        int idx = i * 256 + t;
        if (i < 8 || idx < 2112) {
            int r = idx / 528, f = idx - r * 528;
            int hx = f >> 3, c = f & 7;
            gl16(fprev + ((size_t)((y0 + r) * PW + x0 + hx) * 64 + (c ^ (hx & 7)) * 8),
                 ringF + (size_t)idx * 8);
        }
    }

    // 2. stage r-window [6][68] (rows y0-2..y0+3, cols x0-2..x0+65)
    #pragma unroll
    for (int i = 0; i < 2; ++i) {
        int ix = i * 256 + t;
        if (ix < 408) {
            int row = ix / 68, col = ix - row * 68;
            int gy = y0 - 2 + row, gx = x0 - 2 + col;
            rtile[ix] = ((unsigned)gy < 256u && (unsigned)gx < 256u)
                      ? rm[(gy << 8) + gx] : 0.f;
        }
    }
    asm volatile("s_waitcnt lgkmcnt(0)" ::: "memory");   // rtile ds_writes done
    __builtin_amdgcn_s_barrier();                        // (ringF vmcnt stays)
    __builtin_amdgcn_sched_barrier(0);

    // 3. h-compute from rtile -> ringH (thread owns chunk c8 = t&7)
    {
        const int c8 = t & 7;
        float wreg[72];
        #pragma unroll
        for (int i = 0; i < 18; ++i)
            *(f32x4*)(wreg + i * 4) = *(const f32x4*)(h1w + c8 * 72 + i * 4);
        float b8[8];
        #pragma unroll
        for (int j = 0; j < 8; ++j) b8[j] = h1b[c8 * 8 + j];
        const float hs = h1a[0];

        #pragma unroll
        for (int it = 0; it < 9; ++it) {
            int idx = it * 256 + t;
            if (it < 8 || idx < 2112) {
                int pl = idx >> 3;
                int r  = pl / 66, hx = pl - r * 66;
                int gy = y0 - 1 + r, gx = x0 - 1 + hx;
                half8 o = {0,0,0,0,0,0,0,0};
                if ((unsigned)gy < 256u && (unsigned)gx < 256u) {
                    float v[9];
                    #pragma unroll
                    for (int dy = 0; dy < 3; ++dy)
                        #pragma unroll
                        for (int dx = 0; dx < 3; ++dx)
                            v[dy*3+dx] = rtile[(r + dy) * 68 + hx + dx];
                    #pragma unroll
                    for (int j = 0; j < 8; ++j) {
                        float av = b8[j];
                        #pragma unroll
                        for (int k = 0; k < 9; ++k) av = fmaf(v[k], wreg[j*9+k], av);
                        av = av >= 0.f ? av : hs * av;
                        o[j] = (_Float16)av;
                    }
                }
                *(half8*)(ringH + (size_t)(r * 528 + hx * 8 + (c8 ^ (hx & 7))) * 8) = o;
            }
        }
    }
    __builtin_amdgcn_sched_barrier(0);          // keep A-loads after h-compute

    half8 Areg[36];
    auto load_A = [&](const _Float16* w) {
        #pragma unroll
        for (int tap = 0; tap < 9; ++tap)
            #pragma unroll
            for (int kk = 0; kk < 4; ++kk)
                Areg[tap*4+kk] = *(const half8*)(w +
                    (size_t)(((tap*4+kk)*2 + h)*64 + cobase + cl) * 8);
    };
    load_A(wf);

    f32x16 acc0, acc1;
    #pragma unroll
    for (int q = 0; q < 4; ++q)
        #pragma unroll
        for (int j = 0; j < 4; ++j) {
            float bb = bias[cobase + q * 8 + 4 * h + j];
            acc0[q*4+j] = bb; acc1[q*4+j] = bb;
        }

    __syncthreads();                          // ringF vmcnt + ringH ds drained

    auto cpass = [&](const _Float16* ring) {
        __builtin_amdgcn_s_setprio(1);
        #pragma unroll
        for (int tap = 0; tap < 9; ++tap) {
            const int dy = tap / 3, dx = tap % 3;
            const int hx = px0 + cl + dx;
            const int sw = hx & 7;
            #pragma unroll
            for (int kk = 0; kk < 4; ++kk) {
                const int c = kk * 2 + h;
                half8 b0 = *(const half8*)(ring + ((size_t)(((dy    )*528) + hx*8 + (c ^ sw))) * 8);
                half8 b1 = *(const half8*)(ring + ((size_t)(((dy + 1)*528) + hx*8 + (c ^ sw))) * 8);
                acc0 = __builtin_amdgcn_mfma_f32_32x32x16_f16(Areg[tap*4+kk], b0, acc0, 0, 0, 0);
                acc1 = __builtin_amdgcn_mfma_f32_32x32x16_f16(Areg[tap*4+kk], b1, acc1, 0, 0, 0);
            }
        }
        __builtin_amdgcn_s_setprio(0);
    };

    cpass(ringF);
    load_A(wh);
    cpass(ringH);

    const float slope = alpha[0];
    #pragma unroll
    for (int s = 0; s < 2; ++s) {
        const size_t gp = (size_t)((y0 + s + 1) * PW + (x0 + px0 + cl + 1)) * 64 + cobase;
        const f32x16& A0 = s ? acc1 : acc0;
        #pragma unroll
        for (int q = 0; q < 4; ++q) {
            half4 v;
            #pragma unroll
            for (int j = 0; j < 4; ++j) {
                float xv = A0[q*4+j];
                xv = xv >= 0.f ? xv : slope * xv;
                v[j] = (_Float16)xv;
            }
            *(half4*)(outp + gp + q * 8 + 4 * h) = v;
        }
    }
}

// --------------- t5: conv 64->1, 64px tiles, 8-row walk, 4 blocks/CU
__global__ __launch_bounds__(256, 4)
void t5_k(const _Float16* __restrict__ in_all, const float* __restrict__ w_all,
          const float* __restrict__ b_all, float* __restrict__ out_all)
{
    const int m = blockIdx.y;
    const _Float16* in = in_all + (size_t)m * PLANE;
    const float* w = w_all + m * 576;
    float* outp = out_all + m * NPIX;

    const int t = threadIdx.x;
    const int b = blockIdx.x;
    const int xcd = b & 7, u = b >> 3;
    const int xq = u & 3, band = u >> 2;
    const int y0 = xcd * 32 + band * 8;
    const int x0 = xq << 6;

    __shared__ __align__(16) _Float16 ring[4 * 66 * 64];    // 33792 B
    __shared__ float wl[576];                               //  2304 B
    __shared__ float part[256];                             //  1024 B

    auto stage_row = [&](int pr) {
        const int slot = pr & 3;
        #pragma unroll
        for (int i = 0; i < 3; ++i) {
            int f = i * 256 + t;
            if (f < 528) {
                int hx = f >> 3, c = f & 7;
                gl16(in + ((size_t)(pr * PW + x0 + hx) * 64 + (c ^ (hx & 7)) * 8),
                     ring + (size_t)(slot * 528 + f) * 8);
            }
        }
    };

    stage_row(y0); stage_row(y0 + 1); stage_row(y0 + 2);
    #pragma unroll
    for (int i = 0; i < 3; ++i) { int idx = i*256 + t; if (idx < 576) wl[idx] = w[idx]; }
    __syncthreads();

    const int p5 = t & 63, cq = t >> 6;        // px within tile / chunk-pair
    #pragma unroll 1
    for (int s = 0; s < 8; ++s) {
        if (s < 7) stage_row(y0 + s + 3);
        float acc = 0.f;
        #pragma unroll
        for (int dy = 0; dy < 3; ++dy) {
            const int slot = (y0 + s + dy) & 3;
            #pragma unroll
            for (int dx = 0; dx < 3; ++dx) {
                const int hx = p5 + dx, sw = hx & 7, tap = dy * 3 + dx;
                #pragma unroll
                for (int c2 = 0; c2 < 2; ++c2) {
                    const int c8 = cq * 2 + c2;
                    half8 vv = *(const half8*)(ring +
                        ((size_t)(slot*528 + hx*8 + (c8 ^ sw))) * 8);
                    #pragma unroll
                    for (int e = 0; e < 8; ++e)
                        acc = fmaf((float)vv[e], wl[(c8 * 8 + e) * 9 + tap], acc);
                }
            }
        }
        part[cq * 64 + p5] = acc;
        __syncthreads();
        if (t < 64)
            outp[((y0 + s) << 8) + x0 + t] =
                part[t] + part[64 + t] + part[128 + t] + part[192 + t] + b_all[m];
        __syncthreads();
    }
}

extern "C" void kernel_launch(void* const* d_in, const int* in_sizes, int n_in,
                              void* d_out, int out_size, void* d_ws, size_t ws_size,
                              hipStream_t stream)
{
    const float* x        = (const float*)d_in[0];
    const float* sample_w = (const float*)d_in[1];
    const float* up_w     = (const float*)d_in[2];
    const float* up_b     = (const float*)d_in[3];
    const float* h1_w     = (const float*)d_in[4];
    const float* h1_b     = (const float*)d_in[5];
    const float* h1_a     = (const float*)d_in[6];
    const float* fus_w    = (const float*)d_in[7];
    const float* fus_b    = (const float*)d_in[8];
    const float* fus_a    = (const float*)d_in[9];
    const float* t2_w     = (const float*)d_in[10];
    const float* t2_b     = (const float*)d_in[11];
    const float* t2_a     = (const float*)d_in[12];
    const float* t3_w     = (const float*)d_in[13];
    const float* t3_b     = (const float*)d_in[14];
    const float* t3_a     = (const float*)d_in[15];
    const float* t4_w     = (const float*)d_in[16];
    const float* t4_b     = (const float*)d_in[17];
    const float* t4_a     = (const float*)d_in[18];
    const float* t5_w     = (const float*)d_in[19];
    const float* t5_b     = (const float*)d_in[20];

    float* out = (float*)d_out;
    char*  wsb = (char*)d_ws;

    _Float16* w16    = (_Float16*)wsb;                  //   2,801,664 B
    float*    r_all  = (float*)(wsb + 2801664);         //   2,097,152 B
    _Float16* f_all  = (_Float16*)(wsb + 4898816);      // 8 planes
    _Float16* sc_all = f_all + 8 * PLANE;               // 8 planes
    _Float16* t1_all = sc_all + 8 * PLANE;              // 8 planes

    auto wblk = [&](int b) { return w16 + (size_t)b * 36864; };

    prep_k<<<512, 256, 0, stream>>>(x, sample_w, up_w, up_b,
                                    t2_w, t3_w, t4_w, fus_w,
                                    f_all, w16, r_all);
    h1_k<<<1024, 256, 0, stream>>>(r_all, h1_w, h1_b, h1_a, f_all);

    for (int m = 1; m < 8; ++m) {
        fus_k<<<512, 256, 0, stream>>>(
            f_all + (size_t)(m - 1) * PLANE,
            r_all + m * NPIX, h1_w + m * 576, h1_b + m * 64, h1_a + m,
            wblk(24 + (m - 1) * 2), wblk(24 + (m - 1) * 2 + 1),
            fus_b + (m - 1) * 64, fus_a + (m - 1),
            f_all + (size_t)m * PLANE);
    }

    const size_t LDSB = 66560;                          // 2 blocks/CU
    conv_mfma_k<<<512, 256, LDSB, stream>>>(f_all, wblk(0), t2_b, t2_a, t1_all);
    conv_mfma_k<<<512, 256, LDSB, stream>>>(t1_all, wblk(8), t3_b, t3_a, sc_all);
    conv_mfma_k<<<512, 256, LDSB, stream>>>(sc_all, wblk(16), t4_b, t4_a, t1_all);
    t5_k<<<dim3(128, 8), 256, 0, stream>>>(t1_all, t5_w, t5_b, out);
}

// Round 23
// 343.807 us; speedup vs baseline: 1.0371x; 1.0371x over previous
//
#include <hip/hip_runtime.h>

// HierarchicalCSNet — f16 MFMA implicit-GEMM, 13 dispatches.
// R22 change: conv + t5 LDS rings switched pixel-major -> CHUNK-MAJOR
// ([c][px], chunk idx = c*NPX+hx). B-reads become lane-consecutive 16B
// (zero bank conflicts; old layout had inherent 4-way: every 128B pixel
// row starts at bank 0, XOR only permutes 8 slots). Staging stays legal:
// gl16 dst linear in chunk idx, per-lane global SOURCE does the permute.
constexpr int H = 256, W = 256, NPIX = H * W;
constexpr int PW = 258;
constexpr size_t PLANE = (size_t)PW * PW * 64;

typedef _Float16 half8 __attribute__((ext_vector_type(8)));
typedef _Float16 half4 __attribute__((ext_vector_type(4)));
typedef float    f32x4 __attribute__((ext_vector_type(4)));
typedef float    f32x16 __attribute__((ext_vector_type(16)));

__device__ __forceinline__ void gl16(const _Float16* g, _Float16* l)
{
    __builtin_amdgcn_global_load_lds(
        (const __attribute__((address_space(1))) unsigned int*)g,
        (__attribute__((address_space(3))) unsigned int*)l, 16, 0, 0);
}

// ---------- prep: border zero + weight prep + sampup (grid 512)
__global__ __launch_bounds__(256)
void prep_k(const float* __restrict__ x, const float* __restrict__ sw,
            const float* __restrict__ uw, const float* __restrict__ ub,
            const float* __restrict__ t2w, const float* __restrict__ t3w,
            const float* __restrict__ t4w, const float* __restrict__ fusw,
            _Float16* __restrict__ planes, _Float16* __restrict__ w16,
            float* __restrict__ r_all)
{
    const int b = blockIdx.x, t = threadIdx.x;
    for (int idx = b * 256 + t; idx < 24 * 1028 * 8; idx += 512 * 256) {
        int c = idx & 7, rem = idx >> 3;
        int p = rem / 1028, bb = rem % 1028;
        int gy, gx;
        if (bb < 258)      { gy = 0;            gx = bb; }
        else if (bb < 516) { gy = 257;          gx = bb - 258; }
        else if (bb < 772) { gy = bb - 516 + 1; gx = 0; }
        else               { gy = bb - 772 + 1; gx = 257; }
        f32x4 z = {0.f, 0.f, 0.f, 0.f};
        *(f32x4*)(planes + (size_t)p * PLANE + ((size_t)(gy * PW + gx) * 64) + c * 8) = z;
    }
    for (int idx = b * 256 + t; idx < 38 * 36864; idx += 512 * 256) {
        int blk = idx / 36864, r2 = idx % 36864;
        int e = r2 & 7, co = (r2 >> 3) & 63, hh = (r2 >> 9) & 1, kk = (r2 >> 10) & 3,
            tap = r2 >> 12;
        const float* src; int cin, cib;
        if (blk < 24) {
            int which = blk >> 3, m = blk & 7;
            src = (which == 0 ? t2w : which == 1 ? t3w : t4w) + (size_t)m * 64 * 64 * 9;
            cin = 64; cib = 0;
        } else {
            int f = (blk - 24) >> 1; cib = ((blk - 24) & 1) * 64;
            src = fusw + (size_t)f * 64 * 128 * 9; cin = 128;
        }
        int ci = cib + (kk * 2 + hh) * 8 + e;
        w16[idx] = (_Float16)src[((size_t)co * cin + ci) * 9 + tap];
    }
    {
        int m = b >> 6, ij = b & 63;
        int i = ij >> 3, j = ij & 7;
        __shared__ float s_lds[16];
        if (t < 208) {
            int c = t >> 4, sub = t & 15;
            float acc = 0.f;
            for (int k = sub * 64; k < sub * 64 + 64; ++k) {
                int p = k >> 5, q = k & 31;
                acc += x[(i * 32 + p) * W + (j * 32 + q)] * sw[(m * 13 + c) * 1024 + k];
            }
            #pragma unroll
            for (int off = 8; off; off >>= 1) acc += __shfl_down(acc, off, 16);
            if (sub == 0) s_lds[c] = acc;
        }
        __syncthreads();
        const float* uwm = uw + m * 1024 * 13;
        float* rm = r_all + m * NPIX;
        #pragma unroll
        for (int pi = 0; pi < 4; ++pi) {
            int px = pi * 256 + t;
            int p = px >> 5, q = px & 31;
            int oc = p * 32 + q;
            float acc = ub[m * 1024 + oc];
            #pragma unroll
            for (int c = 0; c < 13; ++c) acc = fmaf(uwm[oc * 13 + c], s_lds[c], acc);
            rm[((i * 32 + p) << 8) + j * 32 + q] = acc;
        }
    }
}

// ---------------- h1 (m=0 only): conv 1->64, writes padded plane f_all[0]
__global__ __launch_bounds__(256)
void h1_k(const float* __restrict__ r_all, const float* __restrict__ w,
          const float* __restrict__ b, const float* __restrict__ a,
          _Float16* __restrict__ f0)
{
    const float* r = r_all;
    const int t = threadIdx.x;
    const int px = t & 63, cog = t >> 6;
    const int y = blockIdx.x >> 2;
    const int x = ((blockIdx.x & 3) << 6) + px;
    float v[9];
    #pragma unroll
    for (int dy = 0; dy < 3; ++dy) {
        int gy = y + dy - 1;
        #pragma unroll
        for (int dx = 0; dx < 3; ++dx) {
            int gx = x + dx - 1;
            v[dy*3+dx] = ((unsigned)gy < 256u && (unsigned)gx < 256u)
                       ? r[(gy << 8) + gx] : 0.f;
        }
    }
    const float slope = a[0];
    _Float16* op = f0 + ((size_t)((y + 1) * PW + (x + 1))) * 64 + cog * 16;
    #pragma unroll
    for (int cg2 = 0; cg2 < 2; ++cg2) {
        half8 o;
        #pragma unroll
        for (int j = 0; j < 8; ++j) {
            int co = cog * 16 + cg2 * 8 + j;
            float acc = b[co];
            #pragma unroll
            for (int k = 0; k < 9; ++k) acc = fmaf(v[k], w[co*9+k], acc);
            acc = acc >= 0.f ? acc : slope * acc;
            o[j] = (_Float16)acc;
        }
        *(half8*)(op + cg2 * 8) = o;
    }
}

// ------- batched conv3x3 (t2/t3/t4): chunk-major ring [4][8c][130px][8]
__global__ __launch_bounds__(256, 2)
void conv_mfma_k(const _Float16* __restrict__ in0, const _Float16* __restrict__ w0,
                 const float* __restrict__ bias, const float* __restrict__ alpha,
                 _Float16* __restrict__ out)
{
    const int t    = threadIdx.x;
    const int lane = t & 63;
    const int wv   = t >> 6;
    const int b    = blockIdx.x;
    const int m    = b >> 6;
    const int rem  = b & 63;
    const int xh   = rem & 1;
    const int y0   = (rem >> 1) << 3;

    const _Float16* inp0 = in0 + (size_t)m * PLANE;
    _Float16*       outp = out + (size_t)m * PLANE;
    const _Float16* wp0  = w0 + (size_t)m * 36864;
    const float*    bp   = bias + m * 64;
    const float     slope = alpha[m];
    const int x0 = xh << 7;

    const int h = lane >> 5, cl = lane & 31;
    const int px0 = (wv & 1) * 64, cobase = (wv >> 1) * 32;

    extern __shared__ __align__(16) char smem[];
    _Float16* li = (_Float16*)smem;            // ring [4][8][130][8] = 66560 B

    half8 Areg[36];
    #pragma unroll
    for (int tap = 0; tap < 9; ++tap)
        #pragma unroll
        for (int kk = 0; kk < 4; ++kk)
            Areg[tap*4+kk] = *(const half8*)(wp0 +
                (size_t)(((tap*4+kk)*2 + h)*64 + cobase + cl) * 8);

    // chunk-major: chunk f = c*130 + hx; gl16 dst linear in f, src per-lane.
    auto stage_row = [&](int pr) {
        const int slot = pr & 3;
        #pragma unroll
        for (int i = 0; i < 5; ++i) {
            int f = i * 256 + t;
            if (i < 4 || f < 1040) {
                int c = f / 130, hx = f - c * 130;
                gl16(inp0 + ((size_t)(pr * PW + x0 + hx) * 64 + c * 8),
                     li + (size_t)(slot * 1040 + f) * 8);
            }
        }
    };

    f32x16 acc0, acc1;

    stage_row(y0); stage_row(y0 + 1); stage_row(y0 + 2);
    __syncthreads();
    #pragma unroll 1
    for (int s = 0; s < 8; ++s) {
        if (s < 7) stage_row(y0 + s + 3);
        #pragma unroll
        for (int q = 0; q < 4; ++q)
            #pragma unroll
            for (int j = 0; j < 4; ++j) {
                float bb = bp[cobase + q * 8 + 4 * h + j];
                acc0[q*4+j] = bb; acc1[q*4+j] = bb;
            }
        __builtin_amdgcn_s_setprio(1);
        #pragma unroll
        for (int tap = 0; tap < 9; ++tap) {
            const int dy = tap / 3, dx = tap % 3;
            const int slot = (y0 + s + dy) & 3;
            const int hx0 = px0 + cl + dx;
            #pragma unroll
            for (int kk = 0; kk < 4; ++kk) {
                const int c = kk * 2 + h;
                const size_t base = (size_t)(slot * 1040 + c * 130);
                half8 b0 = *(const half8*)(li + (base + hx0) * 8);
                half8 b1 = *(const half8*)(li + (base + hx0 + 32) * 8);
                acc0 = __builtin_amdgcn_mfma_f32_32x32x16_f16(Areg[tap*4+kk], b0, acc0, 0, 0, 0);
                acc1 = __builtin_amdgcn_mfma_f32_32x32x16_f16(Areg[tap*4+kk], b1, acc1, 0, 0, 0);
            }
        }
        __builtin_amdgcn_s_setprio(0);
        const int y = y0 + s;
        #pragma unroll
        for (int pt = 0; pt < 2; ++pt) {
            const size_t gp = (size_t)((y + 1) * PW + (x0 + px0 + pt * 32 + cl + 1)) * 64;
            const f32x16& A0 = pt ? acc1 : acc0;
            #pragma unroll
            for (int q = 0; q < 4; ++q) {
                half4 v0;
                #pragma unroll
                for (int j = 0; j < 4; ++j) {
                    float xv = A0[q*4+j];
                    xv = xv >= 0.f ? xv : slope * xv;
                    v0[j] = (_Float16)xv;
                }
                *(half4*)(outp + gp + cobase + q * 8 + 4 * h) = v0;
            }
        }
        if (s < 7) {
            asm volatile("s_waitcnt vmcnt(8)" ::: "memory");
            __builtin_amdgcn_s_barrier();
            __builtin_amdgcn_sched_barrier(0);
        }
    }
}

// ---------------------- fusion (m>=1): unchanged from R21 (proven ~6us)
__global__ __launch_bounds__(256, 2)
void fus_k(const _Float16* __restrict__ fprev, const float* __restrict__ rm,
           const float* __restrict__ h1w, const float* __restrict__ h1b,
           const float* __restrict__ h1a,
           const _Float16* __restrict__ wf, const _Float16* __restrict__ wh,
           const float* __restrict__ bias, const float* __restrict__ alpha,
           _Float16* __restrict__ outp)
{
    const int t = threadIdx.x, lane = t & 63, wv = t >> 6;
    const int b = blockIdx.x;
    const int xcd = b & 7, u = b >> 3, xq = u & 3, band = u >> 2;
    const int y0 = xcd * 32 + band * 2, x0 = xq * 64;
    const int h = lane >> 5, cl = lane & 31;
    const int px0 = (wv & 1) * 32, cobase = (wv >> 1) * 32;

    __shared__ __align__(16) _Float16 ringF[4 * 528 * 8];   // 33792 B
    __shared__ __align__(16) _Float16 ringH[4 * 528 * 8];   // 33792 B
    __shared__ float rtile[6 * 68];                         //  1632 f32

    #pragma unroll
    for (int i = 0; i < 9; ++i) {
        int idx = i * 256 + t;
        if (i < 8 || idx < 2112) {
            int r = idx / 528, f = idx - r * 528;
            int hx = f >> 3, c = f & 7;
            gl16(fprev + ((size_t)((y0 + r) * PW + x0 + hx) * 64 + (c ^ (hx & 7)) * 8),
                 ringF + (size_t)idx * 8);
        }
    }

    #pragma unroll
    for (int i = 0; i < 2; ++i) {
        int ix = i * 256 + t;
        if (ix < 408) {
            int row = ix / 68, col = ix - row * 68;
            int gy = y0 - 2 + row, gx = x0 - 2 + col;
            rtile[ix] = ((unsigned)gy < 256u && (unsigned)gx < 256u)
                      ? rm[(gy << 8) + gx] : 0.f;
        }
    }
    asm volatile("s_waitcnt lgkmcnt(0)" ::: "memory");
    __builtin_amdgcn_s_barrier();
    __builtin_amdgcn_sched_barrier(0);

    {
        const int c8 = t & 7;
        float wreg[72];
        #pragma unroll
        for (int i = 0; i < 18; ++i)
            *(f32x4*)(wreg + i * 4) = *(const f32x4*)(h1w + c8 * 72 + i * 4);
        float b8[8];
        #pragma unroll
        for (int j = 0; j < 8; ++j) b8[j] = h1b[c8 * 8 + j];
        const float hs = h1a[0];

        #pragma unroll
        for (int it = 0; it < 9; ++it) {
            int idx = it * 256 + t;
            if (it < 8 || idx < 2112) {
                int pl = idx >> 3;
                int r  = pl / 66, hx = pl - r * 66;
                int gy = y0 - 1 + r, gx = x0 - 1 + hx;
                half8 o = {0,0,0,0,0,0,0,0};
                if ((unsigned)gy < 256u && (unsigned)gx < 256u) {
                    float v[9];
                    #pragma unroll
                    for (int dy = 0; dy < 3; ++dy)
                        #pragma unroll
                        for (int dx = 0; dx < 3; ++dx)
                            v[dy*3+dx] = rtile[(r + dy) * 68 + hx + dx];
                    #pragma unroll
                    for (int j = 0; j < 8; ++j) {
                        float av = b8[j];
                        #pragma unroll
                        for (int k = 0; k < 9; ++k) av = fmaf(v[k], wreg[j*9+k], av);
                        av = av >= 0.f ? av : hs * av;
                        o[j] = (_Float16)av;
                    }
                }
                *(half8*)(ringH + (size_t)(r * 528 + hx * 8 + (c8 ^ (hx & 7))) * 8) = o;
            }
        }
    }
    __builtin_amdgcn_sched_barrier(0);

    half8 Areg[36];
    auto load_A = [&](const _Float16* w) {
        #pragma unroll
        for (int tap = 0; tap < 9; ++tap)
            #pragma unroll
            for (int kk = 0; kk < 4; ++kk)
                Areg[tap*4+kk] = *(const half8*)(w +
                    (size_t)(((tap*4+kk)*2 + h)*64 + cobase + cl) * 8);
    };
    load_A(wf);

    f32x16 acc0, acc1;
    #pragma unroll
    for (int q = 0; q < 4; ++q)
        #pragma unroll
        for (int j = 0; j < 4; ++j) {
            float bb = bias[cobase + q * 8 + 4 * h + j];
            acc0[q*4+j] = bb; acc1[q*4+j] = bb;
        }

    __syncthreads();

    auto cpass = [&](const _Float16* ring) {
        __builtin_amdgcn_s_setprio(1);
        #pragma unroll
        for (int tap = 0; tap < 9; ++tap) {
            const int dy = tap / 3, dx = tap % 3;
            const int hx = px0 + cl + dx;
            const int sw = hx & 7;
            #pragma unroll
            for (int kk = 0; kk < 4; ++kk) {
                const int c = kk * 2 + h;
                half8 b0 = *(const half8*)(ring + ((size_t)(((dy    )*528) + hx*8 + (c ^ sw))) * 8);
                half8 b1 = *(const half8*)(ring + ((size_t)(((dy + 1)*528) + hx*8 + (c ^ sw))) * 8);
                acc0 = __builtin_amdgcn_mfma_f32_32x32x16_f16(Areg[tap*4+kk], b0, acc0, 0, 0, 0);
                acc1 = __builtin_amdgcn_mfma_f32_32x32x16_f16(Areg[tap*4+kk], b1, acc1, 0, 0, 0);
            }
        }
        __builtin_amdgcn_s_setprio(0);
    };

    cpass(ringF);
    load_A(wh);
    cpass(ringH);

    const float slope = alpha[0];
    #pragma unroll
    for (int s = 0; s < 2; ++s) {
        const size_t gp = (size_t)((y0 + s + 1) * PW + (x0 + px0 + cl + 1)) * 64 + cobase;
        const f32x16& A0 = s ? acc1 : acc0;
        #pragma unroll
        for (int q = 0; q < 4; ++q) {
            half4 v;
            #pragma unroll
            for (int j = 0; j < 4; ++j) {
                float xv = A0[q*4+j];
                xv = xv >= 0.f ? xv : slope * xv;
                v[j] = (_Float16)xv;
            }
            *(half4*)(outp + gp + q * 8 + 4 * h) = v;
        }
    }
}

// --------------- t5: conv 64->1, chunk-major ring [4][8c][66px][8]
__global__ __launch_bounds__(256, 4)
void t5_k(const _Float16* __restrict__ in_all, const float* __restrict__ w_all,
          const float* __restrict__ b_all, float* __restrict__ out_all)
{
    const int m = blockIdx.y;
    const _Float16* in = in_all + (size_t)m * PLANE;
    const float* w = w_all + m * 576;
    float* outp = out_all + m * NPIX;

    const int t = threadIdx.x;
    const int b = blockIdx.x;
    const int xcd = b & 7, u = b >> 3;
    const int xq = u & 3, band = u >> 2;
    const int y0 = xcd * 32 + band * 8;
    const int x0 = xq << 6;

    __shared__ __align__(16) _Float16 ring[4 * 528 * 8];    // 33792 B
    __shared__ float wl[576];
    __shared__ float part[256];

    auto stage_row = [&](int pr) {
        const int slot = pr & 3;
        #pragma unroll
        for (int i = 0; i < 3; ++i) {
            int f = i * 256 + t;
            if (f < 528) {
                int c = f / 66, hx = f - c * 66;
                gl16(in + ((size_t)(pr * PW + x0 + hx) * 64 + c * 8),
                     ring + (size_t)(slot * 528 + f) * 8);
            }
        }
    };

    stage_row(y0); stage_row(y0 + 1); stage_row(y0 + 2);
    #pragma unroll
    for (int i = 0; i < 3; ++i) { int idx = i*256 + t; if (idx < 576) wl[idx] = w[idx]; }
    __syncthreads();

    const int p5 = t & 63, cq = t >> 6;
    #pragma unroll 1
    for (int s = 0; s < 8; ++s) {
        if (s < 7) stage_row(y0 + s + 3);
        float acc = 0.f;
        #pragma unroll
        for (int dy = 0; dy < 3; ++dy) {
            const int slot = (y0 + s + dy) & 3;
            #pragma unroll
            for (int dx = 0; dx < 3; ++dx) {
                const int hx = p5 + dx, tap = dy * 3 + dx;
                #pragma unroll
                for (int c2 = 0; c2 < 2; ++c2) {
                    const int c8 = cq * 2 + c2;
                    half8 vv = *(const half8*)(ring +
                        ((size_t)(slot*528 + c8*66 + hx)) * 8);
                    #pragma unroll
                    for (int e = 0; e < 8; ++e)
                        acc = fmaf((float)vv[e], wl[(c8 * 8 + e) * 9 + tap], acc);
                }
            }
        }
        part[cq * 64 + p5] = acc;
        __syncthreads();
        if (t < 64)
            outp[((y0 + s) << 8) + x0 + t] =
                part[t] + part[64 + t] + part[128 + t] + part[192 + t] + b_all[m];
        __syncthreads();
    }
}

extern "C" void kernel_launch(void* const* d_in, const int* in_sizes, int n_in,
                              void* d_out, int out_size, void* d_ws, size_t ws_size,
                              hipStream_t stream)
{
    const float* x        = (const float*)d_in[0];
    const float* sample_w = (const float*)d_in[1];
    const float* up_w     = (const float*)d_in[2];
    const float* up_b     = (const float*)d_in[3];
    const float* h1_w     = (const float*)d_in[4];
    const float* h1_b     = (const float*)d_in[5];
    const float* h1_a     = (const float*)d_in[6];
    const float* fus_w    = (const float*)d_in[7];
    const float* fus_b    = (const float*)d_in[8];
    const float* fus_a    = (const float*)d_in[9];
    const float* t2_w     = (const float*)d_in[10];
    const float* t2_b     = (const float*)d_in[11];
    const float* t2_a     = (const float*)d_in[12];
    const float* t3_w     = (const float*)d_in[13];
    const float* t3_b     = (const float*)d_in[14];
    const float* t3_a     = (const float*)d_in[15];
    const float* t4_w     = (const float*)d_in[16];
    const float* t4_b     = (const float*)d_in[17];
    const float* t4_a     = (const float*)d_in[18];
    const float* t5_w     = (const float*)d_in[19];
    const float* t5_b     = (const float*)d_in[20];

    float* out = (float*)d_out;
    char*  wsb = (char*)d_ws;

    _Float16* w16    = (_Float16*)wsb;                  //   2,801,664 B
    float*    r_all  = (float*)(wsb + 2801664);         //   2,097,152 B
    _Float16* f_all  = (_Float16*)(wsb + 4898816);      // 8 planes
    _Float16* sc_all = f_all + 8 * PLANE;               // 8 planes
    _Float16* t1_all = sc_all + 8 * PLANE;              // 8 planes

    auto wblk = [&](int b) { return w16 + (size_t)b * 36864; };

    prep_k<<<512, 256, 0, stream>>>(x, sample_w, up_w, up_b,
                                    t2_w, t3_w, t4_w, fus_w,
                                    f_all, w16, r_all);
    h1_k<<<1024, 256, 0, stream>>>(r_all, h1_w, h1_b, h1_a, f_all);

    for (int m = 1; m < 8; ++m) {
        fus_k<<<512, 256, 0, stream>>>(
            f_all + (size_t)(m - 1) * PLANE,
            r_all + m * NPIX, h1_w + m * 576, h1_b + m * 64, h1_a + m,
            wblk(24 + (m - 1) * 2), wblk(24 + (m - 1) * 2 + 1),
            fus_b + (m - 1) * 64, fus_a + (m - 1),
            f_all + (size_t)m * PLANE);
    }

    const size_t LDSB = 66560;                          // 2 blocks/CU
    conv_mfma_k<<<512, 256, LDSB, stream>>>(f_all, wblk(0), t2_b, t2_a, t1_all);
    conv_mfma_k<<<512, 256, LDSB, stream>>>(t1_all, wblk(8), t3_b, t3_a, sc_all);
    conv_mfma_k<<<512, 256, LDSB, stream>>>(sc_all, wblk(16), t4_b, t4_a, t1_all);
    t5_k<<<dim3(128, 8), 256, 0, stream>>>(t1_all, t5_w, t5_b, out);
}

// Round 24
// 340.436 us; speedup vs baseline: 1.0474x; 1.0099x over previous
//
#include <hip/hip_runtime.h>

// HierarchicalCSNet — f16 MFMA implicit-GEMM, 13 dispatches.
// R23 change: conv OUTPUT planes (t1_all/sc_all) switched to chunk-major
// global layout [y][c8][x][8] -> wave store = contiguous 512B (was 8B per
// 64B sector, 1.95x write amplification). f_all stays NHWC (fus reads it).
// conv input mode is a runtime flag: t2 reads NHWC, t3/t4 read chunk-major.
constexpr int H = 256, W = 256, NPIX = H * W;
constexpr int PW = 258;
constexpr size_t PLANE = (size_t)PW * PW * 64;

typedef _Float16 half8 __attribute__((ext_vector_type(8)));
typedef _Float16 half4 __attribute__((ext_vector_type(4)));
typedef float    f32x4 __attribute__((ext_vector_type(4)));
typedef float    f32x16 __attribute__((ext_vector_type(16)));

__device__ __forceinline__ void gl16(const _Float16* g, _Float16* l)
{
    __builtin_amdgcn_global_load_lds(
        (const __attribute__((address_space(1))) unsigned int*)g,
        (__attribute__((address_space(3))) unsigned int*)l, 16, 0, 0);
}

// ---------- prep: border zero (8 NHWC + 16 chunk-major planes) + wprep + sampup
__global__ __launch_bounds__(256)
void prep_k(const float* __restrict__ x, const float* __restrict__ sw,
            const float* __restrict__ uw, const float* __restrict__ ub,
            const float* __restrict__ t2w, const float* __restrict__ t3w,
            const float* __restrict__ t4w, const float* __restrict__ fusw,
            _Float16* __restrict__ fplanes, _Float16* __restrict__ cmplanes,
            _Float16* __restrict__ w16, float* __restrict__ r_all)
{
    const int b = blockIdx.x, t = threadIdx.x;
    // NHWC borders (8 planes): addr (gy*PW+gx)*64 + c*8
    for (int idx = b * 256 + t; idx < 8 * 1028 * 8; idx += 512 * 256) {
        int c = idx & 7, rem = idx >> 3;
        int p = rem / 1028, bb = rem % 1028;
        int gy, gx;
        if (bb < 258)      { gy = 0;            gx = bb; }
        else if (bb < 516) { gy = 257;          gx = bb - 258; }
        else if (bb < 772) { gy = bb - 516 + 1; gx = 0; }
        else               { gy = bb - 772 + 1; gx = 257; }
        f32x4 z = {0.f, 0.f, 0.f, 0.f};
        *(f32x4*)(fplanes + (size_t)p * PLANE + ((size_t)(gy * PW + gx) * 64) + c * 8) = z;
    }
    // chunk-major borders (16 planes): addr ((gy*8+c)*PW+gx)*8
    for (int idx = b * 256 + t; idx < 16 * 1028 * 8; idx += 512 * 256) {
        int c = idx & 7, rem = idx >> 3;
        int p = rem / 1028, bb = rem % 1028;
        int gy, gx;
        if (bb < 258)      { gy = 0;            gx = bb; }
        else if (bb < 516) { gy = 257;          gx = bb - 258; }
        else if (bb < 772) { gy = bb - 516 + 1; gx = 0; }
        else               { gy = bb - 772 + 1; gx = 257; }
        f32x4 z = {0.f, 0.f, 0.f, 0.f};
        *(f32x4*)(cmplanes + (size_t)p * PLANE + ((size_t)((gy * 8 + c) * PW + gx) * 8)) = z;
    }
    for (int idx = b * 256 + t; idx < 38 * 36864; idx += 512 * 256) {
        int blk = idx / 36864, r2 = idx % 36864;
        int e = r2 & 7, co = (r2 >> 3) & 63, hh = (r2 >> 9) & 1, kk = (r2 >> 10) & 3,
            tap = r2 >> 12;
        const float* src; int cin, cib;
        if (blk < 24) {
            int which = blk >> 3, m = blk & 7;
            src = (which == 0 ? t2w : which == 1 ? t3w : t4w) + (size_t)m * 64 * 64 * 9;
            cin = 64; cib = 0;
        } else {
            int f = (blk - 24) >> 1; cib = ((blk - 24) & 1) * 64;
            src = fusw + (size_t)f * 64 * 128 * 9; cin = 128;
        }
        int ci = cib + (kk * 2 + hh) * 8 + e;
        w16[idx] = (_Float16)src[((size_t)co * cin + ci) * 9 + tap];
    }
    {
        int m = b >> 6, ij = b & 63;
        int i = ij >> 3, j = ij & 7;
        __shared__ float s_lds[16];
        if (t < 208) {
            int c = t >> 4, sub = t & 15;
            float acc = 0.f;
            for (int k = sub * 64; k < sub * 64 + 64; ++k) {
                int p = k >> 5, q = k & 31;
                acc += x[(i * 32 + p) * W + (j * 32 + q)] * sw[(m * 13 + c) * 1024 + k];
            }
            #pragma unroll
            for (int off = 8; off; off >>= 1) acc += __shfl_down(acc, off, 16);
            if (sub == 0) s_lds[c] = acc;
        }
        __syncthreads();
        const float* uwm = uw + m * 1024 * 13;
        float* rm = r_all + m * NPIX;
        #pragma unroll
        for (int pi = 0; pi < 4; ++pi) {
            int px = pi * 256 + t;
            int p = px >> 5, q = px & 31;
            int oc = p * 32 + q;
            float acc = ub[m * 1024 + oc];
            #pragma unroll
            for (int c = 0; c < 13; ++c) acc = fmaf(uwm[oc * 13 + c], s_lds[c], acc);
            rm[((i * 32 + p) << 8) + j * 32 + q] = acc;
        }
    }
}

// ---------------- h1 (m=0 only): conv 1->64, writes padded plane f_all[0]
__global__ __launch_bounds__(256)
void h1_k(const float* __restrict__ r_all, const float* __restrict__ w,
          const float* __restrict__ b, const float* __restrict__ a,
          _Float16* __restrict__ f0)
{
    const float* r = r_all;
    const int t = threadIdx.x;
    const int px = t & 63, cog = t >> 6;
    const int y = blockIdx.x >> 2;
    const int x = ((blockIdx.x & 3) << 6) + px;
    float v[9];
    #pragma unroll
    for (int dy = 0; dy < 3; ++dy) {
        int gy = y + dy - 1;
        #pragma unroll
        for (int dx = 0; dx < 3; ++dx) {
            int gx = x + dx - 1;
            v[dy*3+dx] = ((unsigned)gy < 256u && (unsigned)gx < 256u)
                       ? r[(gy << 8) + gx] : 0.f;
        }
    }
    const float slope = a[0];
    _Float16* op = f0 + ((size_t)((y + 1) * PW + (x + 1))) * 64 + cog * 16;
    #pragma unroll
    for (int cg2 = 0; cg2 < 2; ++cg2) {
        half8 o;
        #pragma unroll
        for (int j = 0; j < 8; ++j) {
            int co = cog * 16 + cg2 * 8 + j;
            float acc = b[co];
            #pragma unroll
            for (int k = 0; k < 9; ++k) acc = fmaf(v[k], w[co*9+k], acc);
            acc = acc >= 0.f ? acc : slope * acc;
            o[j] = (_Float16)acc;
        }
        *(half8*)(op + cg2 * 8) = o;
    }
}

// ------- batched conv3x3 (t2/t3/t4): chunk-major ring; chunk-major OUTPUT.
// inmode 0: input NHWC (f_all);  inmode 1: input chunk-major.
__global__ __launch_bounds__(256, 2)
void conv_mfma_k(const _Float16* __restrict__ in0, const _Float16* __restrict__ w0,
                 const float* __restrict__ bias, const float* __restrict__ alpha,
                 _Float16* __restrict__ out, int inmode)
{
    const int t    = threadIdx.x;
    const int lane = t & 63;
    const int wv   = t >> 6;
    const int b    = blockIdx.x;
    const int m    = b >> 6;
    const int rem  = b & 63;
    const int xh   = rem & 1;
    const int y0   = (rem >> 1) << 3;

    const _Float16* inp0 = in0 + (size_t)m * PLANE;
    _Float16*       outp = out + (size_t)m * PLANE;
    const _Float16* wp0  = w0 + (size_t)m * 36864;
    const float*    bp   = bias + m * 64;
    const float     slope = alpha[m];
    const int x0 = xh << 7;

    const int h = lane >> 5, cl = lane & 31;
    const int px0 = (wv & 1) * 64, cobase = (wv >> 1) * 32;

    extern __shared__ __align__(16) char smem[];
    _Float16* li = (_Float16*)smem;            // ring [4][8][130][8] = 66560 B

    half8 Areg[36];
    #pragma unroll
    for (int tap = 0; tap < 9; ++tap)
        #pragma unroll
        for (int kk = 0; kk < 4; ++kk)
            Areg[tap*4+kk] = *(const half8*)(wp0 +
                (size_t)(((tap*4+kk)*2 + h)*64 + cobase + cl) * 8);

    auto stage_row = [&](int pr) {
        const int slot = pr & 3;
        #pragma unroll
        for (int i = 0; i < 5; ++i) {
            int f = i * 256 + t;
            if (i < 4 || f < 1040) {
                int c = f / 130, hx = f - c * 130;
                const _Float16* src = inmode
                    ? inp0 + ((size_t)((pr * 8 + c) * PW + x0 + hx) * 8)
                    : inp0 + ((size_t)(pr * PW + x0 + hx) * 64 + c * 8);
                gl16(src, li + (size_t)(slot * 1040 + f) * 8);
            }
        }
    };

    f32x16 acc0, acc1;

    stage_row(y0); stage_row(y0 + 1); stage_row(y0 + 2);
    __syncthreads();
    #pragma unroll 1
    for (int s = 0; s < 8; ++s) {
        if (s < 7) stage_row(y0 + s + 3);
        #pragma unroll
        for (int q = 0; q < 4; ++q)
            #pragma unroll
            for (int j = 0; j < 4; ++j) {
                float bb = bp[cobase + q * 8 + 4 * h + j];
                acc0[q*4+j] = bb; acc1[q*4+j] = bb;
            }
        __builtin_amdgcn_s_setprio(1);
        #pragma unroll
        for (int tap = 0; tap < 9; ++tap) {
            const int dy = tap / 3, dx = tap % 3;
            const int slot = (y0 + s + dy) & 3;
            const int hx0 = px0 + cl + dx;
            #pragma unroll
            for (int kk = 0; kk < 4; ++kk) {
                const int c = kk * 2 + h;
                const size_t base = (size_t)(slot * 1040 + c * 130);
                half8 b0 = *(const half8*)(li + (base + hx0) * 8);
                half8 b1 = *(const half8*)(li + (base + hx0 + 32) * 8);
                acc0 = __builtin_amdgcn_mfma_f32_32x32x16_f16(Areg[tap*4+kk], b0, acc0, 0, 0, 0);
                acc1 = __builtin_amdgcn_mfma_f32_32x32x16_f16(Areg[tap*4+kk], b1, acc1, 0, 0, 0);
            }
        }
        __builtin_amdgcn_s_setprio(0);
        const int y = y0 + s;
        // chunk-major store: chunk cq = cobase/8 + q; 64 lanes cover a
        // contiguous 512B run per (pt,q) store instruction.
        #pragma unroll
        for (int pt = 0; pt < 2; ++pt) {
            const int gx = x0 + px0 + pt * 32 + cl + 1;
            const f32x16& A0 = pt ? acc1 : acc0;
            #pragma unroll
            for (int q = 0; q < 4; ++q) {
                half4 v0;
                #pragma unroll
                for (int j = 0; j < 4; ++j) {
                    float xv = A0[q*4+j];
                    xv = xv >= 0.f ? xv : slope * xv;
                    v0[j] = (_Float16)xv;
                }
                const int cq = (cobase >> 3) + q;
                *(half4*)(outp + ((size_t)(((y + 1) * 8 + cq) * PW + gx) * 8) + 4 * h) = v0;
            }
        }
        if (s < 7) {
            asm volatile("s_waitcnt vmcnt(8)" ::: "memory");
            __builtin_amdgcn_s_barrier();
            __builtin_amdgcn_sched_barrier(0);
        }
    }
}

// ---------------------- fusion (m>=1): unchanged from R21/R23 (proven ~6us)
__global__ __launch_bounds__(256, 2)
void fus_k(const _Float16* __restrict__ fprev, const float* __restrict__ rm,
           const float* __restrict__ h1w, const float* __restrict__ h1b,
           const float* __restrict__ h1a,
           const _Float16* __restrict__ wf, const _Float16* __restrict__ wh,
           const float* __restrict__ bias, const float* __restrict__ alpha,
           _Float16* __restrict__ outp)
{
    const int t = threadIdx.x, lane = t & 63, wv = t >> 6;
    const int b = blockIdx.x;
    const int xcd = b & 7, u = b >> 3, xq = u & 3, band = u >> 2;
    const int y0 = xcd * 32 + band * 2, x0 = xq * 64;
    const int h = lane >> 5, cl = lane & 31;
    const int px0 = (wv & 1) * 32, cobase = (wv >> 1) * 32;

    __shared__ __align__(16) _Float16 ringF[4 * 528 * 8];   // 33792 B
    __shared__ __align__(16) _Float16 ringH[4 * 528 * 8];   // 33792 B
    __shared__ float rtile[6 * 68];                         //  1632 f32

    #pragma unroll
    for (int i = 0; i < 9; ++i) {
        int idx = i * 256 + t;
        if (i < 8 || idx < 2112) {
            int r = idx / 528, f = idx - r * 528;
            int hx = f >> 3, c = f & 7;
            gl16(fprev + ((size_t)((y0 + r) * PW + x0 + hx) * 64 + (c ^ (hx & 7)) * 8),
                 ringF + (size_t)idx * 8);
        }
    }

    #pragma unroll
    for (int i = 0; i < 2; ++i) {
        int ix = i * 256 + t;
        if (ix < 408) {
            int row = ix / 68, col = ix - row * 68;
            int gy = y0 - 2 + row, gx = x0 - 2 + col;
            rtile[ix] = ((unsigned)gy < 256u && (unsigned)gx < 256u)
                      ? rm[(gy << 8) + gx] : 0.f;
        }
    }
    asm volatile("s_waitcnt lgkmcnt(0)" ::: "memory");
    __builtin_amdgcn_s_barrier();
    __builtin_amdgcn_sched_barrier(0);

    {
        const int c8 = t & 7;
        float wreg[72];
        #pragma unroll
        for (int i = 0; i < 18; ++i)
            *(f32x4*)(wreg + i * 4) = *(const f32x4*)(h1w + c8 * 72 + i * 4);
        float b8[8];
        #pragma unroll
        for (int j = 0; j < 8; ++j) b8[j] = h1b[c8 * 8 + j];
        const float hs = h1a[0];

        #pragma unroll
        for (int it = 0; it < 9; ++it) {
            int idx = it * 256 + t;
            if (it < 8 || idx < 2112) {
                int pl = idx >> 3;
                int r  = pl / 66, hx = pl - r * 66;
                int gy = y0 - 1 + r, gx = x0 - 1 + hx;
                half8 o = {0,0,0,0,0,0,0,0};
                if ((unsigned)gy < 256u && (unsigned)gx < 256u) {
                    float v[9];
                    #pragma unroll
                    for (int dy = 0; dy < 3; ++dy)
                        #pragma unroll
                        for (int dx = 0; dx < 3; ++dx)
                            v[dy*3+dx] = rtile[(r + dy) * 68 + hx + dx];
                    #pragma unroll
                    for (int j = 0; j < 8; ++j) {
                        float av = b8[j];
                        #pragma unroll
                        for (int k = 0; k < 9; ++k) av = fmaf(v[k], wreg[j*9+k], av);
                        av = av >= 0.f ? av : hs * av;
                        o[j] = (_Float16)av;
                    }
                }
                *(half8*)(ringH + (size_t)(r * 528 + hx * 8 + (c8 ^ (hx & 7))) * 8) = o;
            }
        }
    }
    __builtin_amdgcn_sched_barrier(0);

    half8 Areg[36];
    auto load_A = [&](const _Float16* w) {
        #pragma unroll
        for (int tap = 0; tap < 9; ++tap)
            #pragma unroll
            for (int kk = 0; kk < 4; ++kk)
                Areg[tap*4+kk] = *(const half8*)(w +
                    (size_t)(((tap*4+kk)*2 + h)*64 + cobase + cl) * 8);
    };
    load_A(wf);

    f32x16 acc0, acc1;
    #pragma unroll
    for (int q = 0; q < 4; ++q)
        #pragma unroll
        for (int j = 0; j < 4; ++j) {
            float bb = bias[cobase + q * 8 + 4 * h + j];
            acc0[q*4+j] = bb; acc1[q*4+j] = bb;
        }

    __syncthreads();

    auto cpass = [&](const _Float16* ring) {
        __builtin_amdgcn_s_setprio(1);
        #pragma unroll
        for (int tap = 0; tap < 9; ++tap) {
            const int dy = tap / 3, dx = tap % 3;
            const int hx = px0 + cl + dx;
            const int sw = hx & 7;
            #pragma unroll
            for (int kk = 0; kk < 4; ++kk) {
                const int c = kk * 2 + h;
                half8 b0 = *(const half8*)(ring + ((size_t)(((dy    )*528) + hx*8 + (c ^ sw))) * 8);
                half8 b1 = *(const half8*)(ring + ((size_t)(((dy + 1)*528) + hx*8 + (c ^ sw))) * 8);
                acc0 = __builtin_amdgcn_mfma_f32_32x32x16_f16(Areg[tap*4+kk], b0, acc0, 0, 0, 0);
                acc1 = __builtin_amdgcn_mfma_f32_32x32x16_f16(Areg[tap*4+kk], b1, acc1, 0, 0, 0);
            }
        }
        __builtin_amdgcn_s_setprio(0);
    };

    cpass(ringF);
    load_A(wh);
    cpass(ringH);

    const float slope = alpha[0];
    #pragma unroll
    for (int s = 0; s < 2; ++s) {
        const size_t gp = (size_t)((y0 + s + 1) * PW + (x0 + px0 + cl + 1)) * 64 + cobase;
        const f32x16& A0 = s ? acc1 : acc0;
        #pragma unroll
        for (int q = 0; q < 4; ++q) {
            half4 v;
            #pragma unroll
            for (int j = 0; j < 4; ++j) {
                float xv = A0[q*4+j];
                xv = xv >= 0.f ? xv : slope * xv;
                v[j] = (_Float16)xv;
            }
            *(half4*)(outp + gp + q * 8 + 4 * h) = v;
        }
    }
}

// --------------- t5: conv 64->1, chunk-major ring + chunk-major input
__global__ __launch_bounds__(256, 4)
void t5_k(const _Float16* __restrict__ in_all, const float* __restrict__ w_all,
          const float* __restrict__ b_all, float* __restrict__ out_all)
{
    const int m = blockIdx.y;
    const _Float16* in = in_all + (size_t)m * PLANE;
    const float* w = w_all + m * 576;
    float* outp = out_all + m * NPIX;

    const int t = threadIdx.x;
    const int b = blockIdx.x;
    const int xcd = b & 7, u = b >> 3;
    const int xq = u & 3, band = u >> 2;
    const int y0 = xcd * 32 + band * 8;
    const int x0 = xq << 6;

    __shared__ __align__(16) _Float16 ring[4 * 528 * 8];    // 33792 B
    __shared__ float wl[576];
    __shared__ float part[256];

    auto stage_row = [&](int pr) {
        const int slot = pr & 3;
        #pragma unroll
        for (int i = 0; i < 3; ++i) {
            int f = i * 256 + t;
            if (f < 528) {
                int c = f / 66, hx = f - c * 66;
                gl16(in + ((size_t)((pr * 8 + c) * PW + x0 + hx) * 8),
                     ring + (size_t)(slot * 528 + f) * 8);
            }
        }
    };

    stage_row(y0); stage_row(y0 + 1); stage_row(y0 + 2);
    #pragma unroll
    for (int i = 0; i < 3; ++i) { int idx = i*256 + t; if (idx < 576) wl[idx] = w[idx]; }
    __syncthreads();

    const int p5 = t & 63, cq = t >> 6;
    #pragma unroll 1
    for (int s = 0; s < 8; ++s) {
        if (s < 7) stage_row(y0 + s + 3);
        float acc = 0.f;
        #pragma unroll
        for (int dy = 0; dy < 3; ++dy) {
            const int slot = (y0 + s + dy) & 3;
            #pragma unroll
            for (int dx = 0; dx < 3; ++dx) {
                const int hx = p5 + dx, tap = dy * 3 + dx;
                #pragma unroll
                for (int c2 = 0; c2 < 2; ++c2) {
                    const int c8 = cq * 2 + c2;
                    half8 vv = *(const half8*)(ring +
                        ((size_t)(slot*528 + c8*66 + hx)) * 8);
                    #pragma unroll
                    for (int e = 0; e < 8; ++e)
                        acc = fmaf((float)vv[e], wl[(c8 * 8 + e) * 9 + tap], acc);
                }
            }
        }
        part[cq * 64 + p5] = acc;
        __syncthreads();
        if (t < 64)
            outp[((y0 + s) << 8) + x0 + t] =
                part[t] + part[64 + t] + part[128 + t] + part[192 + t] + b_all[m];
        __syncthreads();
    }
}

extern "C" void kernel_launch(void* const* d_in, const int* in_sizes, int n_in,
                              void* d_out, int out_size, void* d_ws, size_t ws_size,
                              hipStream_t stream)
{
    const float* x        = (const float*)d_in[0];
    const float* sample_w = (const float*)d_in[1];
    const float* up_w     = (const float*)d_in[2];
    const float* up_b     = (const float*)d_in[3];
    const float* h1_w     = (const float*)d_in[4];
    const float* h1_b     = (const float*)d_in[5];
    const float* h1_a     = (const float*)d_in[6];
    const float* fus_w    = (const float*)d_in[7];
    const float* fus_b    = (const float*)d_in[8];
    const float* fus_a    = (const float*)d_in[9];
    const float* t2_w     = (const float*)d_in[10];
    const float* t2_b     = (const float*)d_in[11];
    const float* t2_a     = (const float*)d_in[12];
    const float* t3_w     = (const float*)d_in[13];
    const float* t3_b     = (const float*)d_in[14];
    const float* t3_a     = (const float*)d_in[15];
    const float* t4_w     = (const float*)d_in[16];
    const float* t4_b     = (const float*)d_in[17];
    const float* t4_a     = (const float*)d_in[18];
    const float* t5_w     = (const float*)d_in[19];
    const float* t5_b     = (const float*)d_in[20];

    float* out = (float*)d_out;
    char*  wsb = (char*)d_ws;

    _Float16* w16    = (_Float16*)wsb;                  //   2,801,664 B
    float*    r_all  = (float*)(wsb + 2801664);         //   2,097,152 B
    _Float16* f_all  = (_Float16*)(wsb + 4898816);      // 8 NHWC planes
    _Float16* sc_all = f_all + 8 * PLANE;               // 8 chunk-major planes
    _Float16* t1_all = sc_all + 8 * PLANE;              // 8 chunk-major planes

    auto wblk = [&](int b) { return w16 + (size_t)b * 36864; };

    prep_k<<<512, 256, 0, stream>>>(x, sample_w, up_w, up_b,
                                    t2_w, t3_w, t4_w, fus_w,
                                    f_all, sc_all, w16, r_all);
    h1_k<<<1024, 256, 0, stream>>>(r_all, h1_w, h1_b, h1_a, f_all);

    for (int m = 1; m < 8; ++m) {
        fus_k<<<512, 256, 0, stream>>>(
            f_all + (size_t)(m - 1) * PLANE,
            r_all + m * NPIX, h1_w + m * 576, h1_b + m * 64, h1_a + m,
            wblk(24 + (m - 1) * 2), wblk(24 + (m - 1) * 2 + 1),
            fus_b + (m - 1) * 64, fus_a + (m - 1),
            f_all + (size_t)m * PLANE);
    }

    const size_t LDSB = 66560;                          // 2 blocks/CU
    conv_mfma_k<<<512, 256, LDSB, stream>>>(f_all, wblk(0), t2_b, t2_a, t1_all, 0);
    conv_mfma_k<<<512, 256, LDSB, stream>>>(t1_all, wblk(8), t3_b, t3_a, sc_all, 1);
    conv_mfma_k<<<512, 256, LDSB, stream>>>(sc_all, wblk(16), t4_b, t4_a, t1_all, 1);
    t5_k<<<dim3(128, 8), 256, 0, stream>>>(t1_all, t5_w, t5_b, out);
}